// Round 5
// baseline (12809.204 us; speedup 1.0000x reference)
//
#include <hip/hip_runtime.h>
#include <hip/hip_bf16.h>

#define B_ 64
#define T_ 512
#define D_ 256
#define H_ 1024
#define RING 64          // h-history ring depth
#define SLOTU 16         // uints per seq slot (64 B per jgroup)
#define SLOTB (B_*H_*2)  // bytes per ring slot (128 KB)

typedef __attribute__((ext_vector_type(8))) short short8;
typedef __attribute__((ext_vector_type(4))) float floatx4;

__device__ __forceinline__ unsigned short f2bf(float f){
  unsigned u = __builtin_bit_cast(unsigned, f);
  u = (u + 0x7fffu + ((u >> 16) & 1u)) >> 16;
  return (unsigned short)u;
}
__device__ __forceinline__ short8 pack8(floatx4 a, floatx4 b){
  short8 r;
  r[0]=(short)f2bf(a[0]); r[1]=(short)f2bf(a[1]); r[2]=(short)f2bf(a[2]); r[3]=(short)f2bf(a[3]);
  r[4]=(short)f2bf(b[0]); r[5]=(short)f2bf(b[1]); r[6]=(short)f2bf(b[2]); r[7]=(short)f2bf(b[3]);
  return r;
}
__device__ __forceinline__ float sigm(float v){ return 1.f/(1.f+__expf(-v)); }
__device__ __forceinline__ float tanh_f(float v){ return 1.f - 2.f/(1.f+__expf(2.f*v)); }

// async global->LDS, 16 B per lane: LDS dest = uniform base + lane*16
__device__ __forceinline__ void gload_lds16(const void* g, void* l){
  __builtin_amdgcn_global_load_lds(
    (const __attribute__((address_space(1))) unsigned int*)g,
    (__attribute__((address_space(3))) unsigned int*)l, 16, 0, 0);
}

// h ring storage layout (per slot): row r (0..63), col c (0..1023), granule = 8 cols:
//   byte = r*2048 + ((c>>3) ^ (r&7))*16 + (c&7)*2   -- swizzle keeps the unpadded
// LDS image conflict-free for A-frag ds_read_b128 (8 lanes per 4-bank group = b128 floor).

// Block: 512 thr = 8 waves = 8 K-slices; M=32 (batch half), N=64 gate rows (16 h-cols).
// LAYER 0: K = 256 x (fp32, direct regs) + 1024 h0 (LDS-staged).
// LAYER 1: K = 1024 h0 + 1024 h1 (both LDS-staged).
template<int LAYER>
__device__ __forceinline__ void run_lstm(
    const float* __restrict__ x,
    const float* __restrict__ Wi, const float* __restrict__ Wh,
    const float* __restrict__ bi, const float* __restrict__ bh_,
    unsigned* seq, char* h0h, char* h1h, float* h1f,
    int jg, int bhalf,
    unsigned short* h0p, unsigned short* h1p, float* gate, float* c_st, float* biasv)
{
  constexpr int NKS = LAYER ? 8 : 5;      // ks per wave: L0 = 1 x-ks + 4 h-ks; L1 = 4 h0 + 4 h1
  const int tid = threadIdx.x;
  const int wv  = tid >> 6;               // K-slice id 0..7
  const int lane = tid & 63;
  const int n15 = lane & 15;
  const int kq  = lane >> 4;              // 0..3
  const int jbase = jg * 16;

  // ---- one-time: weights -> registers (bf16); nt indexes the gate (i,f,g,o)
  short8 bw[4][NKS];
  #pragma unroll
  for (int nt = 0; nt < 4; nt++){
    const int wrow = nt*H_ + jbase + n15;
    #pragma unroll
    for (int ks = 0; ks < NKS; ks++){
      const float* s;
      if constexpr (LAYER == 0){
        if (ks == 0) s = Wi + (size_t)wrow*D_ + wv*32 + kq*8;                 // x part
        else         s = Wh + (size_t)wrow*H_ + wv*128 + (ks-1)*32 + kq*8;    // h0 part
      } else {
        if (ks < 4)  s = Wi + (size_t)wrow*H_ + wv*128 + ks*32 + kq*8;        // h0 part
        else         s = Wh + (size_t)wrow*H_ + wv*128 + (ks-4)*32 + kq*8;    // h1 part
      }
      bw[nt][ks] = pack8(*(const floatx4*)s, *(const floatx4*)(s+4));
    }
  }
  if (tid < 64){
    int col = (tid >> 4)*H_ + jbase + (tid & 15);
    biasv[tid] = bi[col] + bh_[col];
  }
  c_st[tid & 511] = 0.f;
  for (int i = tid; i < 32*66; i += 512) gate[i] = 0.f;
  __syncthreads();

  // lane j watches jgroup j of this bhalf: 8 B = (layer0 seq, layer1 seq)
  unsigned long long* watch = (unsigned long long*)(seq + (size_t)lane*SLOTU + bhalf*2);

  for (int t = 0; t < T_; t++){
    floatx4 acc[2][4];
    #pragma unroll
    for (int mt = 0; mt < 2; mt++)
      #pragma unroll
      for (int nt = 0; nt < 4; nt++) acc[mt][nt] = (floatx4)0.f;

    // ---- layer0: x-part loads + MFMAs (input-independent, before any wait)
    if constexpr (LAYER == 0){
      short8 ax[2];
      #pragma unroll
      for (int mt = 0; mt < 2; mt++){
        const float* xs = x + ((size_t)(bhalf*32 + mt*16 + n15)*T_ + t)*D_ + wv*32 + kq*8;
        ax[mt] = pack8(*(const floatx4*)xs, *(const floatx4*)(xs+4));
      }
      #pragma unroll
      for (int mt = 0; mt < 2; mt++)
        #pragma unroll
        for (int nt = 0; nt < 4; nt++)
          acc[mt][nt] = __builtin_amdgcn_mfma_f32_16x16x32_bf16(ax[mt], bw[nt][0], acc[mt][nt], 0, 0, 0);
    }

    // ---- dataflow wait (every wave polls; relaxed agent loads, no cache maintenance)
    {
      unsigned tgt0, tgt1;
      if (LAYER == 0){ tgt0 = (unsigned)t; tgt1 = (t >= RING) ? (unsigned)(t-RING+1) : 0u; }
      else           { tgt0 = (unsigned)(t+1); tgt1 = (unsigned)t; }
      if (tgt0 | tgt1){
        long g = 0;
        for (;;){
          unsigned long long v = __hip_atomic_load(watch, __ATOMIC_RELAXED, __HIP_MEMORY_SCOPE_AGENT);
          unsigned v0 = (unsigned)v, v1 = (unsigned)(v >> 32);
          if (__all(v0 >= tgt0 && v1 >= tgt1)) break;
          __builtin_amdgcn_s_sleep(2);
          if (++g > (1L<<22)) break;   // safety valve; never hit in correct runs
        }
      }
    }

    // ---- stage h panels into LDS (64 chunks of 1 KB per panel, 8 per wave, all in flight)
    const int s0 = (LAYER ? t : t-1) & (RING-1);
    if (LAYER == 1 || t > 0){
      const char* src = h0h + (size_t)s0*SLOTB;
      #pragma unroll
      for (int c = 0; c < 8; c++){
        int p = (wv*8 + c) >> 1, cc = (wv*8 + c) & 1;
        gload_lds16(src + (size_t)(bhalf*32 + p)*2048 + cc*1024 + lane*16,
                    (char*)h0p + p*2048 + cc*1024);
      }
    }
    if (LAYER == 1 && t > 0){
      const char* src = h1h + (size_t)((t-1) & (RING-1))*SLOTB;
      #pragma unroll
      for (int c = 0; c < 8; c++){
        int p = (wv*8 + c) >> 1, cc = (wv*8 + c) & 1;
        gload_lds16(src + (size_t)(bhalf*32 + p)*2048 + cc*1024 + lane*16,
                    (char*)h1p + p*2048 + cc*1024);
      }
    }
    __syncthreads();   // drains vmcnt (staging) + joins waves

    // ---- h MFMAs from LDS (swizzled, conflict-free b128 reads)
    if (LAYER == 1 || t > 0){
      const int hks = 4;  // h0 k-steps per wave
      #pragma unroll
      for (int ks = 0; ks < hks; ks++){
        const int g = wv*16 + ks*4 + kq;          // granule index in row
        #pragma unroll
        for (int mt = 0; mt < 2; mt++){
          const int m = mt*16 + n15;
          short8 a = *(const short8*)((const char*)h0p + m*2048 + ((g ^ (m&7))*16));
          #pragma unroll
          for (int nt = 0; nt < 4; nt++)
            acc[mt][nt] = __builtin_amdgcn_mfma_f32_16x16x32_bf16(
                a, bw[nt][LAYER ? ks : ks+1], acc[mt][nt], 0, 0, 0);
        }
      }
    }
    if (LAYER == 1 && t > 0){
      #pragma unroll
      for (int ks = 0; ks < 4; ks++){
        const int g = wv*16 + ks*4 + kq;
        #pragma unroll
        for (int mt = 0; mt < 2; mt++){
          const int m = mt*16 + n15;
          short8 a = *(const short8*)((const char*)h1p + m*2048 + ((g ^ (m&7))*16));
          #pragma unroll
          for (int nt = 0; nt < 4; nt++)
            acc[mt][nt] = __builtin_amdgcn_mfma_f32_16x16x32_bf16(
                a, bw[nt][ks+4], acc[mt][nt], 0, 0, 0);
        }
      }
    }

    // ---- cross-wave K-reduction: LDS float atomics into gate[32][66]
    #pragma unroll
    for (int mt = 0; mt < 2; mt++)
      #pragma unroll
      for (int nt = 0; nt < 4; nt++)
        #pragma unroll
        for (int r = 0; r < 4; r++){
          int b = mt*16 + kq*4 + r;      // C layout: row=(lane>>4)*4+r
          int n = nt*16 + n15;           // col=lane&15
          atomicAdd(&gate[b*66 + n], acc[mt][nt][r]);
        }
    __syncthreads();

    // ---- epilogue: gates(+bias) -> (c,h); write-through swizzled h store; re-zero gate
    if (tid < 256){
      const int b = tid >> 3, jj0 = (tid & 7)*2;
      unsigned short hb[2]; float hf[2];
      #pragma unroll
      for (int u = 0; u < 2; u++){
        const int jj = jj0 + u;
        float gg[4];
        #pragma unroll
        for (int q = 0; q < 4; q++){
          gg[q] = gate[b*66 + q*16 + jj] + biasv[q*16 + jj];   // <-- R4 bug: bias was missing
          gate[b*66 + q*16 + jj] = 0.f;
        }
        float co = c_st[b*16 + jj];
        float si = sigm(gg[0]), sf = sigm(gg[1]), tg = tanh_f(gg[2]), so = sigm(gg[3]);
        float cn = sf*co + si*tg;
        float hn = so*tanh_f(cn);
        c_st[b*16 + jj] = cn;
        hb[u] = f2bf(hn); hf[u] = hn;
      }
      const int row = bhalf*32 + b, col = jbase + jj0;
      char* dst = (LAYER ? h1h : h0h) + (size_t)(t & (RING-1))*SLOTB
                + (size_t)row*2048 + (((col>>3) ^ (row&7))*16) + (col&7)*2;
      unsigned pk = (unsigned)hb[0] | ((unsigned)hb[1] << 16);
      __hip_atomic_store((unsigned*)dst, pk, __ATOMIC_RELAXED, __HIP_MEMORY_SCOPE_AGENT);
      if (LAYER == 1 && t == T_-1){
        h1f[(size_t)row*H_ + col]     = hf[0];
        h1f[(size_t)row*H_ + col + 1] = hf[1];
      }
    }
    __syncthreads();   // all stores drained (vmcnt) before the post
    if (tid == 0)
      __hip_atomic_store(seq + (size_t)jg*SLOTU + bhalf*2 + LAYER, (unsigned)(t+1),
                         __ATOMIC_RELAXED, __HIP_MEMORY_SCOPE_AGENT);
  }
}

__global__ __launch_bounds__(512, 2) void lstm_pk(
    const float* __restrict__ x,
    const float* __restrict__ Wih0, const float* __restrict__ Whh0,
    const float* __restrict__ bih0, const float* __restrict__ bhh0,
    const float* __restrict__ Wih1, const float* __restrict__ Whh1,
    const float* __restrict__ bih1, const float* __restrict__ bhh1,
    char* __restrict__ ws)
{
  __shared__ unsigned short h0p[32*1024];   // 64 KB staged h0 panel (unpadded, swizzled)
  __shared__ unsigned short h1p[32*1024];   // 64 KB staged h1 panel
  __shared__ float gate[32*66];             // 8.4 KB reduced gate matrix
  __shared__ float c_st[512];
  __shared__ float biasv[64];

  unsigned* seq = (unsigned*)ws;                       // 64 jgroups x 64 B: [jg]{bh0:(L0,L1), bh1:(L0,L1)}
  char* h0h = ws + (1<<20);                            // RING x 128 KB (8 MB)
  char* h1h = ws + (1<<20) + (size_t)RING*SLOTB;       // 8 MB
  float* h1f = (float*)(ws + (1<<20) + 2*(size_t)RING*SLOTB);  // [64][1024] fp32

  const int bid = blockIdx.x;
  if (bid < 128)
    run_lstm<0>(x, Wih0, Whh0, bih0, bhh0, seq, h0h, h1h, h1f, bid>>1, bid&1,
                h0p, h1p, gate, c_st, biasv);
  else
    run_lstm<1>(x, Wih1, Whh1, bih1, bhh1, seq, h0h, h1h, h1f, (bid-128)>>1, (bid-128)&1,
                h0p, h1p, gate, c_st, biasv);
}

__global__ __launch_bounds__(128) void fc_k(
    const float* __restrict__ h1f, const float* __restrict__ Wfc,
    const float* __restrict__ bfc, float* __restrict__ out)
{
  __shared__ float hv[1024];
  int b = blockIdx.x, c = threadIdx.x;
  for (int i = c; i < 1024; i += 128) hv[i] = h1f[(size_t)b*1024 + i];
  __syncthreads();
  const floatx4* w4 = (const floatx4*)(Wfc + (size_t)c*1024);
  const floatx4* h4 = (const floatx4*)hv;
  float acc = 0.f;
  #pragma unroll 8
  for (int k = 0; k < 256; k++){
    floatx4 wv = w4[k];
    floatx4 hh = h4[k];
    acc += wv[0]*hh[0] + wv[1]*hh[1] + wv[2]*hh[2] + wv[3]*hh[3];
  }
  out[(size_t)b*128 + c] = acc + bfc[c];
}

extern "C" void kernel_launch(void* const* d_in, const int* in_sizes, int n_in,
                              void* d_out, int out_size, void* d_ws, size_t ws_size,
                              hipStream_t stream)
{
  const float* x    = (const float*)d_in[0];
  const float* Wih0 = (const float*)d_in[1];
  const float* Whh0 = (const float*)d_in[2];
  const float* bih0 = (const float*)d_in[3];
  const float* bhh0 = (const float*)d_in[4];
  const float* Wih1 = (const float*)d_in[5];
  const float* Whh1 = (const float*)d_in[6];
  const float* bih1 = (const float*)d_in[7];
  const float* bhh1 = (const float*)d_in[8];
  const float* Wfc  = (const float*)d_in[9];
  const float* bfc  = (const float*)d_in[10];

  // zero only the seq flags (ring slots are written before first read; t=0 paths predicated)
  hipMemsetAsync(d_ws, 0, 64*SLOTU*sizeof(unsigned), stream);

  lstm_pk<<<256, 512, 0, stream>>>(x, Wih0, Whh0, bih0, bhh0, Wih1, Whh1, bih1, bhh1, (char*)d_ws);

  const float* h1f = (const float*)((char*)d_ws + (1<<20) + 2*(size_t)RING*SLOTB);
  fc_k<<<64, 128, 0, stream>>>(h1f, Wfc, bfc, (float*)d_out);
}

// Round 7
// 9065.175 us; speedup vs baseline: 1.4130x; 1.4130x over previous
//
#include <hip/hip_runtime.h>
#include <hip/hip_bf16.h>

#define B_ 64
#define T_ 512
#define D_ 256
#define H_ 1024
#define RING 64          // h-history ring depth (slot reuse after 64 steps)
#define NBLK 64          // blocks per layer

typedef __attribute__((ext_vector_type(8))) short short8;
typedef __attribute__((ext_vector_type(4))) float floatx4;

__device__ __forceinline__ unsigned short f2bf(float f){
  unsigned u = __builtin_bit_cast(unsigned, f);
  u = (u + 0x7fffu + ((u >> 16) & 1u)) >> 16;
  return (unsigned short)u;
}
__device__ __forceinline__ short8 pack8(floatx4 a, floatx4 b){
  short8 r;
  r[0]=(short)f2bf(a[0]); r[1]=(short)f2bf(a[1]); r[2]=(short)f2bf(a[2]); r[3]=(short)f2bf(a[3]);
  r[4]=(short)f2bf(b[0]); r[5]=(short)f2bf(b[1]); r[6]=(short)f2bf(b[2]); r[7]=(short)f2bf(b[3]);
  return r;
}
__device__ __forceinline__ float sigm(float v){ return 1.f/(1.f+__expf(-v)); }
__device__ __forceinline__ float tanh_f(float v){ return 1.f - 2.f/(1.f+__expf(2.f*v)); }

// LAYER 0: K = 256 (x, fp32) + 1024 (h0).  LAYER 1: K = 1024 (h0) + 1024 (h1).
// Block: 512 thr = 8 waves = 4 K-slices x 2 N-halves; owns 16 h-cols (64 gate rows).
// Flags: pairs[64][2] = (f0,f1) per jgroup, contiguous 512 B. Per-wave masked waits.
template<int LAYER>
__device__ __forceinline__ void run_lstm(
    const float* __restrict__ x,
    const float* __restrict__ Wi, const float* __restrict__ Wh,
    const float* __restrict__ bi, const float* __restrict__ bh_,
    unsigned* pairs, unsigned short* h0r, unsigned short* h1r, float* h1f,
    int jbase, int myblk,
    float* partial /*[4][64][66]*/, float* c_st /*[64][16]*/, float* biasv /*[64]*/)
{
  constexpr int KTOT = LAYER ? 2048 : 1280;
  constexpr int KW   = KTOT/4;          // per-k-slice K extent (512 / 320)
  constexpr int NK   = KW/32;           // k-steps per wave (16 / 10)
  constexpr int KA   = LAYER ? 1024 : 256;  // Wi K extent (h part starts here)

  const int tid   = threadIdx.x;
  const int wave  = tid >> 6;
  const int lane  = tid & 63;
  const int nhalf = wave >> 2;          // which 32 gate rows
  const int ksl   = wave & 3;           // which K slice
  const int n15   = lane & 15;
  const int kq    = (lane >> 4) * 8;

  // ---- one-time: weights -> registers (bf16)
  short8 bfr[2][NK];
  #pragma unroll
  for (int nt = 0; nt < 2; nt++){
    int n   = nhalf*32 + nt*16 + n15;
    int row = (n >> 4)*H_ + jbase + (n & 15);
    #pragma unroll
    for (int ks = 0; ks < NK; ks++){
      int k = ksl*KW + ks*32 + kq;
      const float* s = (k < KA) ? (Wi + (size_t)row*KA + k)
                                : (Wh + (size_t)row*H_ + (k - KA));
      bfr[nt][ks] = pack8(*(const floatx4*)s, *(const floatx4*)(s + 4));
    }
  }
  if (tid < 64){
    int col = (tid >> 4)*H_ + jbase + (tid & 15);
    biasv[tid] = bi[col] + bh_[col];
  }
  c_st[tid] = 0.f; c_st[tid + 512] = 0.f;   // full [64][16] = 1024 entries (R6 bug: was [512])
  __syncthreads();

  // ---- per-wave dependency masks over the 64 jgroups (bit j = need producer j)
  unsigned long long m0, m1;
  if (LAYER == 0){
    // k-slice -> h0 col range: ksl0:[0,64) ksl1:[64,384) ksl2:[384,704) ksl3:[704,1024)
    const unsigned long long t0[4] = {0xFull, 0xFFFFF0ull, 0xFFFFF000000ull, 0xFFFFF00000000000ull};
    m0 = t0[ksl];
    m1 = ~0ull;                          // WAR: h0 slot reuse vs all layer-1 readers (lag 64)
  } else {
    m0 = (ksl==0) ? 0xFFFFFFFFull : (ksl==1) ? 0xFFFFFFFF00000000ull : 0ull;  // h0 halves
    m1 = (ksl==2) ? 0xFFFFFFFFull : (ksl==3) ? 0xFFFFFFFF00000000ull : 0ull;  // h1 halves (also bounds skew<=63)
  }
  const bool need0 = (m0 >> lane) & 1;
  const bool need1 = (m1 >> lane) & 1;
  unsigned long long* watch = (unsigned long long*)(pairs + 2*lane);

  for (int t = 0; t < T_; t++){
    floatx4 acc[4][2];
    #pragma unroll
    for (int mt = 0; mt < 4; mt++)
      #pragma unroll
      for (int nt = 0; nt < 2; nt++)
        acc[mt][nt] = (floatx4)0.f;

    // ---- L0 ksl0: x-part (k<256) loads + MFMAs, no dependency -> before the wait
    if constexpr (LAYER == 0){
      if (ksl == 0){
        #pragma unroll
        for (int ks = 0; ks < 8; ks++){
          const int kk = ks*32 + kq;
          short8 ax[4];
          #pragma unroll
          for (int mt = 0; mt < 4; mt++){
            const float* xs = x + ((size_t)(mt*16 + n15)*T_ + t)*D_ + kk;
            ax[mt] = pack8(*(const floatx4*)xs, *(const floatx4*)(xs+4));
          }
          #pragma unroll
          for (int mt = 0; mt < 4; mt++)
            #pragma unroll
            for (int nt = 0; nt < 2; nt++)
              acc[mt][nt] = __builtin_amdgcn_mfma_f32_16x16x32_bf16(ax[mt], bfr[nt][ks], acc[mt][nt], 0, 0, 0);
        }
      }
    }

    // ---- masked dataflow wait: this wave blocks only on producers it reads
    {
      unsigned tgt0, tgt1;
      if (LAYER == 0){ tgt0 = (unsigned)t; tgt1 = (t >= RING) ? (unsigned)(t-RING+1) : 0u; }
      else           { tgt0 = (unsigned)(t+1); tgt1 = (unsigned)t; }
      if (tgt0 | tgt1){
        long g = 0;
        for (;;){
          unsigned long long v = __hip_atomic_load(watch, __ATOMIC_RELAXED, __HIP_MEMORY_SCOPE_AGENT);
          unsigned v0 = (unsigned)v, v1 = (unsigned)(v >> 32);
          bool ok = (!need0 || v0 >= tgt0) && (!need1 || v1 >= tgt1);
          if (__all(ok)) break;
          __builtin_amdgcn_s_sleep(2);
          if (++g > (1L<<22)) break;   // safety valve; never hit in correct runs
        }
      }
    }

    const unsigned short* h0t = h0r + (size_t)((LAYER ? t : (t-1)) & (RING-1)) * (B_*H_);
    const unsigned short* h1t = h1r + (size_t)((t-1) & (RING-1)) * (B_*H_);

    #pragma unroll
    for (int ks = 0; ks < NK; ks++){
      const int kb = ksl*KW + ks*32;
      if (LAYER == 0 && kb < 256) continue;   // x part hoisted above
      if (kb >= KA && t == 0) continue;       // h[-1] = 0 (wave-uniform)
      const int kk = kb + kq;
      short8 afr[4];
      if constexpr (LAYER == 0){
        const unsigned short* base = h0t + (kk - 256);
        #pragma unroll
        for (int mt = 0; mt < 4; mt++)
          afr[mt] = *(const short8*)(base + (size_t)(mt*16 + n15)*H_);
      } else {
        const unsigned short* base = (kb < 1024) ? (h0t + kk) : (h1t + (kk - 1024));
        #pragma unroll
        for (int mt = 0; mt < 4; mt++)
          afr[mt] = *(const short8*)(base + (size_t)(mt*16 + n15)*H_);
      }
      #pragma unroll
      for (int mt = 0; mt < 4; mt++)
        #pragma unroll
        for (int nt = 0; nt < 2; nt++)
          acc[mt][nt] = __builtin_amdgcn_mfma_f32_16x16x32_bf16(afr[mt], bfr[nt][ks], acc[mt][nt], 0, 0, 0);
    }

    // ---- spill K-slice partials to LDS (C layout: col=lane&15, row=(lane>>4)*4+r)
    #pragma unroll
    for (int mt = 0; mt < 4; mt++)
      #pragma unroll
      for (int nt = 0; nt < 2; nt++)
        #pragma unroll
        for (int r = 0; r < 4; r++){
          int b = mt*16 + (lane >> 4)*4 + r;
          int n = nhalf*32 + nt*16 + n15;
          partial[((size_t)ksl*64 + b)*66 + n] = acc[mt][nt][r];
        }
    __syncthreads();

    // ---- gate reduction + nonlinearities + write-through h store
    {
      int b = tid >> 3, jj0 = (tid & 7)*2;
      unsigned short hb[2]; float hf[2];
      #pragma unroll
      for (int u = 0; u < 2; u++){
        int jj = jj0 + u;
        float g[4];
        #pragma unroll
        for (int q = 0; q < 4; q++){
          int n = q*16 + jj;
          g[q] = partial[(0*64 + b)*66 + n] + partial[(1*64 + b)*66 + n]
               + partial[(2*64 + b)*66 + n] + partial[(3*64 + b)*66 + n] + biasv[n];
        }
        float co = c_st[b*16 + jj];
        float si = sigm(g[0]), sf = sigm(g[1]), tg = tanh_f(g[2]), so = sigm(g[3]);
        float cn = sf*co + si*tg;
        float hn = so*tanh_f(cn);
        c_st[b*16 + jj] = cn;
        hb[u] = f2bf(hn); hf[u] = hn;
      }
      unsigned pk = (unsigned)hb[0] | ((unsigned)hb[1] << 16);
      unsigned short* dst = (LAYER ? h1r : h0r)
                          + (size_t)(t & (RING-1))*(B_*H_) + (size_t)b*H_ + jbase + jj0;
      __hip_atomic_store((unsigned*)dst, pk, __ATOMIC_RELAXED, __HIP_MEMORY_SCOPE_AGENT);
      if (LAYER == 1 && t == T_-1){
        h1f[(size_t)b*H_ + jbase + jj0]     = hf[0];
        h1f[(size_t)b*H_ + jbase + jj0 + 1] = hf[1];
      }
    }
    __syncthreads();   // drains vmcnt in every wave (h stores visible) before the post
    if (tid == 0)
      __hip_atomic_store(pairs + 2*myblk + LAYER, (unsigned)(t+1),
                         __ATOMIC_RELAXED, __HIP_MEMORY_SCOPE_AGENT);
  }
}

__global__ __launch_bounds__(512, 2) void lstm_pk(
    const float* __restrict__ x,
    const float* __restrict__ Wih0, const float* __restrict__ Whh0,
    const float* __restrict__ bih0, const float* __restrict__ bhh0,
    const float* __restrict__ Wih1, const float* __restrict__ Whh1,
    const float* __restrict__ bih1, const float* __restrict__ bhh1,
    char* __restrict__ ws)
{
  __shared__ float partial[4*64*66];   // 67.6 KB, stride 66 -> 2-way banks (free)
  __shared__ float c_st[1024];         // [64 batch][16 cols]
  __shared__ float biasv[64];

  unsigned* pairs     = (unsigned*)ws;                                    // [64][2] = (f0,f1) per jgroup, 512 B
  unsigned short* h0r = (unsigned short*)(ws + (1<<20));                  // RING x [64][1024] bf16 (8 MB)
  unsigned short* h1r = (unsigned short*)(ws + (1<<20) + RING*B_*H_*2);   // 8 MB
  float* h1f          = (float*)(ws + (1<<20) + 2*(size_t)RING*B_*H_*2);  // [64][1024] fp32

  const int bid = blockIdx.x;
  if (bid < NBLK)
    run_lstm<0>(x, Wih0, Whh0, bih0, bhh0, pairs, h0r, h1r, h1f, bid*16, bid, partial, c_st, biasv);
  else
    run_lstm<1>(x, Wih1, Whh1, bih1, bhh1, pairs, h0r, h1r, h1f, (bid-NBLK)*16, bid-NBLK, partial, c_st, biasv);
}

__global__ __launch_bounds__(128) void fc_k(
    const float* __restrict__ h1f, const float* __restrict__ Wfc,
    const float* __restrict__ bfc, float* __restrict__ out)
{
  __shared__ float hv[1024];
  int b = blockIdx.x, c = threadIdx.x;
  for (int i = c; i < 1024; i += 128) hv[i] = h1f[(size_t)b*1024 + i];
  __syncthreads();
  const floatx4* w4 = (const floatx4*)(Wfc + (size_t)c*1024);
  const floatx4* h4 = (const floatx4*)hv;
  float acc = 0.f;
  #pragma unroll 8
  for (int k = 0; k < 256; k++){
    floatx4 wv = w4[k];
    floatx4 hh = h4[k];
    acc += wv[0]*hh[0] + wv[1]*hh[1] + wv[2]*hh[2] + wv[3]*hh[3];
  }
  out[(size_t)b*128 + c] = acc + bfc[c];
}

extern "C" void kernel_launch(void* const* d_in, const int* in_sizes, int n_in,
                              void* d_out, int out_size, void* d_ws, size_t ws_size,
                              hipStream_t stream)
{
  const float* x    = (const float*)d_in[0];
  const float* Wih0 = (const float*)d_in[1];
  const float* Whh0 = (const float*)d_in[2];
  const float* bih0 = (const float*)d_in[3];
  const float* bhh0 = (const float*)d_in[4];
  const float* Wih1 = (const float*)d_in[5];
  const float* Whh1 = (const float*)d_in[6];
  const float* bih1 = (const float*)d_in[7];
  const float* bhh1 = (const float*)d_in[8];
  const float* Wfc  = (const float*)d_in[9];
  const float* bfc  = (const float*)d_in[10];

  // zero only the flag pairs (ring slots written before first read; t=0 paths predicated)
  hipMemsetAsync(d_ws, 0, 4096, stream);

  lstm_pk<<<2*NBLK, 512, 0, stream>>>(x, Wih0, Whh0, bih0, bhh0, Wih1, Whh1, bih1, bhh1, (char*)d_ws);

  const float* h1f = (const float*)((char*)d_ws + (1<<20) + 2*(size_t)RING*B_*H_*2);
  fc_k<<<64, 128, 0, stream>>>(h1f, Wfc, bfc, (float*)d_out);
}